// Round 4
// baseline (5485.636 us; speedup 1.0000x reference)
//
#include <hip/hip_runtime.h>
#include <hip/hip_bf16.h>

typedef unsigned short u16;
typedef unsigned int u32;
typedef __attribute__((ext_vector_type(4))) float f32x4;
typedef __attribute__((ext_vector_type(8))) short bf16x8;

#define DEV static __device__ __forceinline__

DEV float bf2f(u16 u) { u32 x = ((u32)u) << 16; return __builtin_bit_cast(float, x); }
DEV u16 f2bf(float f) {
  __hip_bfloat16 h = __float2bfloat16(f);
  return __builtin_bit_cast(u16, h);
}

DEV void gld16(const u16* g, u16* l) {
  __builtin_amdgcn_global_load_lds((const __attribute__((address_space(1))) void*)g,
                                   (__attribute__((address_space(3))) void*)l, 16, 0, 0);
}

// ---------------------------------------------------------------- convert
__global__ void cvt_bf16(const float* __restrict__ s, u16* __restrict__ d, int n) {
  int i = blockIdx.x * 256 + threadIdx.x;
  if (i < n) d[i] = f2bf(s[i]);
}

// ---------------------------------------------------------------- layernorm (one wave per 512-row, bf16 out)
__global__ __launch_bounds__(256)
void ln_bf16(const float* __restrict__ src, const float* __restrict__ g,
             const float* __restrict__ b, u16* __restrict__ dst) {
  const int row = blockIdx.x * 4 + (threadIdx.x >> 6);
  const int lane = threadIdx.x & 63;
  const float* p = src + (long)row * 512 + lane * 8;
  float x[8];
  *(float4*)&x[0] = *(const float4*)p;
  *(float4*)&x[4] = *(const float4*)(p + 4);
  float s = 0.f;
#pragma unroll
  for (int e = 0; e < 8; ++e) s += x[e];
#pragma unroll
  for (int off = 32; off; off >>= 1) s += __shfl_xor(s, off, 64);
  const float mean = s * (1.0f / 512.0f);
  float q = 0.f;
#pragma unroll
  for (int e = 0; e < 8; ++e) { float d = x[e] - mean; q += d * d; }
#pragma unroll
  for (int off = 32; off; off >>= 1) q += __shfl_xor(q, off, 64);
  const float rinv = rsqrtf(q * (1.0f / 512.0f) + 1e-5f);
  u16 o[8];
  const int c0 = lane * 8;
#pragma unroll
  for (int e = 0; e < 8; ++e) o[e] = f2bf((x[e] - mean) * rinv * g[c0 + e] + b[c0 + e]);
  *(uint4*)(dst + (long)row * 512 + c0) = *(uint4*)o;
}

// ---------------------------------------------------------------- GEMM (NT), 256x256 tile.
// 2-slot LDS double-buffer (64 KiB) -> 2 blocks/CU co-resident: cross-block
// MFMA/VMEM overlap (m114 mechanism) replaces in-block deep prefetch, which
// rounds 1-3 showed is neutral at 1 block/CU. T2 piece-XOR swizzle retained
// (bank conflicts measured 0). Plain __syncthreads per K-tile: the drain is
// hidden by the co-resident block.
enum { EPI_QKV = 0, EPI_PROJ = 1, EPI_GELU = 2, EPI_FC2 = 3 };

template <int EPI>
__global__ __launch_bounds__(512, 4)
void gemm256(const u16* __restrict__ A, const u16* __restrict__ W,
             const float* __restrict__ bias, const float* __restrict__ res,
             void* __restrict__ outv, int M, int N, int K) {
  // LDS: 2 slots x (A: 256x32 bf16 = 8192 el | B: 8192 el) = 65536 B
  extern __shared__ u16 sm[];
  (void)M;
  const int t = threadIdx.x;
  const int lane = t & 63;
  const int wave = t >> 6;
  const int wm = wave >> 2;   // 0..1 -> 128-row half
  const int wn = wave & 3;    // 0..3 -> 64-col quarter
  const long m0 = (long)blockIdx.y * 256;
  const long n0 = (long)blockIdx.x * 256;

  // staging: one gld16 instr = 512 thr x 16B = 128 rows x 64B. row = t>>2; physical piece t&3
  // holds global piece (t&3)^((row>>1)&3)  (T2 involution, source-side)
  const int sr = t >> 2;
  const int sc = ((t & 3) ^ ((sr >> 1) & 3)) * 8;
  const u16* gA0 = A + (m0 + sr) * (long)K + sc;
  const u16* gA1 = gA0 + 128L * K;
  const u16* gB0 = W + (n0 + sr) * (long)K + sc;
  const u16* gB1 = gB0 + 128L * K;
  u16* lws = sm + wave * 512;  // wave-uniform LDS base; HW adds lane*16B

  const int NT = K >> 5;  // K-tiles of 32
  f32x4 acc[8][4] = {};
  // read side: lane holds logical k-piece p=(lane>>4); physical piece = p ^ ((fr>>1)&3)
  // ((row>>1)&3) == ((fr>>1)&3) for all sub-tiles since i*16, wm*128, wn*64 are ≡0 mod 8
  const int fr = lane & 15;
  const int kp = ((lane >> 4) ^ ((fr >> 1) & 3)) * 8;

#define STAGE(slot, tile)                      \
  do {                                         \
    const int _k = (tile) * 32;                \
    u16* _b = lws + (slot) * 16384;            \
    gld16(gA0 + _k, _b);                       \
    gld16(gA1 + _k, _b + 4096);                \
    gld16(gB0 + _k, _b + 8192);                \
    gld16(gB1 + _k, _b + 12288);               \
  } while (0)

#define COMPUTE(slot)                                                                           \
  do {                                                                                          \
    const u16* Ab = sm + (slot) * 16384 + (wm * 128 + fr) * 32 + kp;                            \
    const u16* Bb = sm + (slot) * 16384 + 8192 + (wn * 64 + fr) * 32 + kp;                      \
    bf16x8 af[8], bfv[4];                                                                       \
    _Pragma("unroll")                                                                           \
    for (int i = 0; i < 8; ++i) af[i] = *(const bf16x8*)(Ab + i * 512);                         \
    _Pragma("unroll")                                                                           \
    for (int j = 0; j < 4; ++j) bfv[j] = *(const bf16x8*)(Bb + j * 512);                        \
    __builtin_amdgcn_s_setprio(1);                                                              \
    _Pragma("unroll")                                                                           \
    for (int i = 0; i < 8; ++i)                                                                 \
      _Pragma("unroll")                                                                         \
      for (int j = 0; j < 4; ++j)                                                               \
        acc[i][j] = __builtin_amdgcn_mfma_f32_16x16x32_bf16(af[i], bfv[j], acc[i][j], 0, 0, 0); \
    __builtin_amdgcn_s_setprio(0);                                                              \
  } while (0)

  // prologue: stage tile 0 (drain at syncthreads)
  STAGE(0, 0);
  __syncthreads();

  // steady state: stage next slot, compute current, full sync (drain hidden by
  // the co-resident block on this CU)
  int kt = 0;
  for (; kt < NT - 1; ++kt) {
    STAGE((kt + 1) & 1, kt + 1);   // issue-early, before ds_reads of current
    COMPUTE(kt & 1);
    __syncthreads();
  }
  COMPUTE(kt & 1);
#undef STAGE
#undef COMPUTE

  // epilogue. C/D: col = lane&15, row = (lane>>4)*4 + reg
  const int col = lane & 15;
  const int rq = (lane >> 4) * 4;
#pragma unroll
  for (int mi = 0; mi < 8; ++mi) {
#pragma unroll
    for (int ni = 0; ni < 4; ++ni) {
#pragma unroll
      for (int r = 0; r < 4; ++r) {
        const long m = m0 + wm * 128 + mi * 16 + rq + r;
        const long n = n0 + wn * 64 + ni * 16 + col;
        const float v = acc[mi][ni][r] + bias[n];
        const long idx = m * (long)N + n;
        if constexpr (EPI == EPI_QKV) {
          ((u16*)outv)[idx] = f2bf(v);
        } else if constexpr (EPI == EPI_PROJ) {
          ((float*)outv)[idx] = v + res[idx];
        } else if constexpr (EPI == EPI_GELU) {
          ((u16*)outv)[idx] = f2bf(0.5f * v * (1.0f + erff(v * 0.70710678118f)));
        } else {  // EPI_FC2
          ((float*)outv)[idx] = v + res[idx];
        }
      }
    }
  }
}

// ---------------------------------------------------------------- MFMA windowed attention
// one block per window; 4 waves x 4 heads each
constexpr int SS_S = 68;  // S^T stride (elems); 8B-aligned b64 writes
constexpr int VT_S = 72;  // V^T stride (elems); 16B-aligned b128 reads

__global__ __launch_bounds__(256)
void attn_mfma(const u16* __restrict__ qkv, const float* __restrict__ mmap,
               const float* __restrict__ rpb, u16* __restrict__ outp) {
  __shared__ u16 SSb[4 * 64 * SS_S];   // 34816 B
  __shared__ u16 Vtb[4 * 32 * VT_S];   // 18432 B
  __shared__ u16 rpb_s[16 * 226];      // 7232 B
  __shared__ float mw[64];
  __shared__ int tok[64];
  __shared__ int regi[64];

  const int t = threadIdx.x;
  const int lane = t & 63, wave = t >> 6;
  const int c = lane & 15, q = lane >> 4;
  const int win = blockIdx.x;
  const int b = win >> 6, wh = (win >> 3) & 7, ww = win & 7;

  if (t < 64) {
    const int i = t >> 3, j = t & 7;
    const int hs = wh * 8 + i, wsv = ww * 8 + j;       // shifted-frame coords
    const int h = (hs + 4) & 63, w = (wsv + 4) & 63;   // original coords
    const int tk = b * 4096 + h * 64 + w;
    tok[t] = tk;
    mw[t] = fminf(fmaxf(mmap[tk], 0.f), 1.f);
    regi[t] = (hs < 56 ? 0 : (hs < 60 ? 1 : 2)) * 3 + (wsv < 56 ? 0 : (wsv < 60 ? 1 : 2));
  }
  for (int id = t; id < 3600; id += 256) {
    const int h = id & 15, idx = id >> 4;
    rpb_s[h * 226 + idx] = f2bf(rpb[id]);
  }
  __syncthreads();

  u16* SS = SSb + wave * 64 * SS_S;
  u16* Vt = Vtb + wave * 32 * VT_S;

  // hoisted per-lane state
  int tQ[4];
  float mwn[16], mwm[4];
  int rgn[16], rgm[4];
#pragma unroll
  for (int i = 0; i < 4; ++i) tQ[i] = tok[16 * i + c];
#pragma unroll
  for (int i = 0; i < 4; ++i)
#pragma unroll
    for (int r = 0; r < 4; ++r) {
      const int n = 16 * i + 4 * q + r;
      mwn[i * 4 + r] = mw[n];
      rgn[i * 4 + r] = regi[n];
    }
#pragma unroll
  for (int j = 0; j < 4; ++j) {
    const int m = 16 * j + c;
    mwm[j] = mw[m];
    rgm[j] = regi[m];
  }
  const int imc = c >> 3, jmc = c & 7;  // col m = 16j+c: im = 2j+imc, jm = jmc
  const int tV = tok[lane];
  const float scale = 0.17677669529663687f;  // 1/sqrt(32)

  for (int hi = 0; hi < 4; ++hi) {
    const int head = wave * 4 + hi;

    // Q/K fragments: A/B layout [m=lane&15][k=q*8+j], direct from global
    bf16x8 qf[4], kf[4];
#pragma unroll
    for (int i = 0; i < 4; ++i) {
      const u16* base = qkv + (long)tQ[i] * 1536 + head * 32 + q * 8;
      qf[i] = *(const bf16x8*)(base);
      kf[i] = *(const bf16x8*)(base + 512);
    }

    // stage V transposed: Vt[d][token]
    {
      const u16* vp = qkv + (long)tV * 1536 + 1024 + head * 32;
      u16 vv[32];
      *(uint4*)&vv[0]  = *(const uint4*)(vp);
      *(uint4*)&vv[8]  = *(const uint4*)(vp + 8);
      *(uint4*)&vv[16] = *(const uint4*)(vp + 16);
      *(uint4*)&vv[24] = *(const uint4*)(vp + 24);
#pragma unroll
      for (int d = 0; d < 32; ++d) Vt[d * VT_S + lane] = vv[d];
    }

    // QK^T: S[n][m], tiles i (rows n), j (cols m)
    f32x4 acc[4][4] = {};
#pragma unroll
    for (int i = 0; i < 4; ++i)
#pragma unroll
      for (int j = 0; j < 4; ++j)
        acc[i][j] = __builtin_amdgcn_mfma_f32_16x16x32_bf16(qf[i], kf[j], acc[i][j], 0, 0, 0);

    // bias + softmax in registers (lane holds rows n=16i+4q+r, cols m=16j+c)
    const u16* rb = rpb_s + head * 226;
    float rmx[16], rsum[16];
#pragma unroll
    for (int i = 0; i < 4; ++i)
#pragma unroll
      for (int r = 0; r < 4; ++r) {
        const int n = 16 * i + 4 * q + r;
        const int inr = n >> 3, jnr = n & 7;
        float mx = -1e30f;
#pragma unroll
        for (int j = 0; j < 4; ++j) {
          const int di = inr - 2 * j - imc + 7;
          const int dj = jnr - jmc + 7;
          float s = acc[i][j][r] * scale + bf2f(rb[di * 15 + dj]) +
                    0.5f * (mwn[i * 4 + r] + mwm[j]);
          if (rgn[i * 4 + r] != rgm[j]) s -= 100.f;
          acc[i][j][r] = s;
          mx = fmaxf(mx, s);
        }
        rmx[i * 4 + r] = mx;
      }
#pragma unroll
    for (int ir = 0; ir < 16; ++ir)
#pragma unroll
      for (int msk = 1; msk < 16; msk <<= 1)
        rmx[ir] = fmaxf(rmx[ir], __shfl_xor(rmx[ir], msk, 64));
#pragma unroll
    for (int i = 0; i < 4; ++i)
#pragma unroll
      for (int r = 0; r < 4; ++r) {
        float sm = 0.f;
#pragma unroll
        for (int j = 0; j < 4; ++j) {
          const float e = __expf(acc[i][j][r] - rmx[i * 4 + r]);
          acc[i][j][r] = e;
          sm += e;
        }
        rsum[i * 4 + r] = sm;
      }
#pragma unroll
    for (int ir = 0; ir < 16; ++ir) {
#pragma unroll
      for (int msk = 1; msk < 16; msk <<= 1)
        rsum[ir] += __shfl_xor(rsum[ir], msk, 64);
      rsum[ir] = 1.0f / rsum[ir];
    }

    // write SS = S^T (bf16), packed b64: SS[m][n..n+3]
#pragma unroll
    for (int i = 0; i < 4; ++i)
#pragma unroll
      for (int j = 0; j < 4; ++j) {
        ushort4 pk;
        pk.x = f2bf(acc[i][j][0] * rsum[i * 4 + 0]);
        pk.y = f2bf(acc[i][j][1] * rsum[i * 4 + 1]);
        pk.z = f2bf(acc[i][j][2] * rsum[i * 4 + 2]);
        pk.w = f2bf(acc[i][j][3] * rsum[i * 4 + 3]);
        *(ushort4*)&SS[(16 * j + c) * SS_S + 16 * i + 4 * q] = pk;
      }

    __syncthreads();  // writes (Vt, SS) -> reads, all waves in lockstep

    // PV: O^T = Vt(32x64) * S^T(64x64)
    bf16x8 av[2][2];
#pragma unroll
    for (int mi = 0; mi < 2; ++mi)
#pragma unroll
      for (int ki = 0; ki < 2; ++ki)
        av[mi][ki] = *(const bf16x8*)&Vt[(16 * mi + c) * VT_S + 32 * ki + 8 * q];

    f32x4 oacc[2][4] = {};
#pragma unroll
    for (int ki = 0; ki < 2; ++ki)
#pragma unroll
      for (int ni = 0; ni < 4; ++ni) {
        union { u16 h[8]; bf16x8 v; } ub;
#pragma unroll
        for (int jj = 0; jj < 8; ++jj)
          ub.h[jj] = SS[(32 * ki + 8 * q + jj) * SS_S + 16 * ni + c];
#pragma unroll
        for (int mi = 0; mi < 2; ++mi)
          oacc[mi][ni] = __builtin_amdgcn_mfma_f32_16x16x32_bf16(av[mi][ki], ub.v, oacc[mi][ni], 0, 0, 0);
      }

    // store O: D col = token n = 16ni+c, row = d = 16mi+4q+r (r contiguous -> 8B stores)
#pragma unroll
    for (int ni = 0; ni < 4; ++ni) {
      u16* ob = outp + (long)tQ[ni] * 512 + head * 32;
#pragma unroll
      for (int mi = 0; mi < 2; ++mi) {
        ushort4 pk;
        pk.x = f2bf(oacc[mi][ni][0]);
        pk.y = f2bf(oacc[mi][ni][1]);
        pk.z = f2bf(oacc[mi][ni][2]);
        pk.w = f2bf(oacc[mi][ni][3]);
        *(ushort4*)(ob + 16 * mi + 4 * q) = pk;
      }
    }
    __syncthreads();  // reads done before next iteration's writes
  }
}

// ---------------------------------------------------------------- launch
extern "C" void kernel_launch(void* const* d_in, const int* in_sizes, int n_in,
                              void* d_out, int out_size, void* d_ws, size_t ws_size,
                              hipStream_t stream) {
  (void)in_sizes; (void)n_in; (void)out_size; (void)ws_size;
  const float* x      = (const float*)d_in[0];
  const float* mmap   = (const float*)d_in[1];
  const float* n1g    = (const float*)d_in[2];
  const float* n1b    = (const float*)d_in[3];
  const float* qkv_w  = (const float*)d_in[4];
  const float* qkv_b  = (const float*)d_in[5];
  const float* proj_w = (const float*)d_in[6];
  const float* proj_b = (const float*)d_in[7];
  const float* rpb    = (const float*)d_in[8];
  const float* n2g    = (const float*)d_in[9];
  const float* n2b    = (const float*)d_in[10];
  const float* fc1_w  = (const float*)d_in[11];
  const float* fc1_b  = (const float*)d_in[12];
  const float* fc2_w  = (const float*)d_in[13];
  const float* fc2_b  = (const float*)d_in[14];
  float* out = (float*)d_out;
  char* ws = (char*)d_ws;

  u16*   ybf   = (u16*)(ws);                  // 64 MB : LN1 out, later LN2 out
  u16*   qkvbf = (u16*)(ws + (64L  << 20));   // 192 MB
  u16*   attno = (u16*)(ws + (256L << 20));   // 64 MB
  float* x1    = (float*)(ws + (320L << 20)); // 128 MB
  u16*   hbuf  = qkvbf;                       // 256 MB, reuses qkvbf+attno region
  u16*   wqkv  = (u16*)(ws + (448L << 20));
  u16*   wproj = wqkv + 1536 * 512;
  u16*   wfc1  = wproj + 512 * 512;
  u16*   wfc2  = wfc1 + 2048 * 512;

  static bool smem_init = false;
  if (!smem_init) {
    smem_init = true;
    (void)hipFuncSetAttribute(reinterpret_cast<const void*>(gemm256<EPI_QKV>),
                              hipFuncAttributeMaxDynamicSharedMemorySize, 65536);
    (void)hipFuncSetAttribute(reinterpret_cast<const void*>(gemm256<EPI_PROJ>),
                              hipFuncAttributeMaxDynamicSharedMemorySize, 65536);
    (void)hipFuncSetAttribute(reinterpret_cast<const void*>(gemm256<EPI_GELU>),
                              hipFuncAttributeMaxDynamicSharedMemorySize, 65536);
    (void)hipFuncSetAttribute(reinterpret_cast<const void*>(gemm256<EPI_FC2>),
                              hipFuncAttributeMaxDynamicSharedMemorySize, 65536);
  }

  cvt_bf16<<<1536 * 512 / 256, 256, 0, stream>>>(qkv_w, wqkv, 1536 * 512);
  cvt_bf16<<<512 * 512 / 256, 256, 0, stream>>>(proj_w, wproj, 512 * 512);
  cvt_bf16<<<2048 * 512 / 256, 256, 0, stream>>>(fc1_w, wfc1, 2048 * 512);
  cvt_bf16<<<512 * 2048 / 256, 256, 0, stream>>>(fc2_w, wfc2, 512 * 2048);

  ln_bf16<<<16384, 256, 0, stream>>>(x, n1g, n1b, ybf);
  gemm256<EPI_QKV><<<dim3(6, 256), 512, 65536, stream>>>(ybf, wqkv, qkv_b, nullptr, qkvbf, 65536, 1536, 512);
  attn_mfma<<<1024, 256, 0, stream>>>(qkvbf, mmap, rpb, attno);
  gemm256<EPI_PROJ><<<dim3(2, 256), 512, 65536, stream>>>(attno, wproj, proj_b, x, x1, 65536, 512, 512);
  ln_bf16<<<16384, 256, 0, stream>>>(x1, n2g, n2b, ybf);
  gemm256<EPI_GELU><<<dim3(8, 256), 512, 65536, stream>>>(ybf, wfc1, fc1_b, nullptr, hbuf, 65536, 2048, 512);
  gemm256<EPI_FC2><<<dim3(2, 256), 512, 65536, stream>>>(hbuf, wfc2, fc2_b, x1, out, 65536, 512, 2048);
}

// Round 5
// 1050.440 us; speedup vs baseline: 5.2222x; 5.2222x over previous
//
#include <hip/hip_runtime.h>
#include <hip/hip_bf16.h>

typedef unsigned short u16;
typedef unsigned int u32;
typedef __attribute__((ext_vector_type(4))) float f32x4;
typedef __attribute__((ext_vector_type(8))) short bf16x8;

#define DEV static __device__ __forceinline__

DEV float bf2f(u16 u) { u32 x = ((u32)u) << 16; return __builtin_bit_cast(float, x); }
DEV u16 f2bf(float f) {
  __hip_bfloat16 h = __float2bfloat16(f);
  return __builtin_bit_cast(u16, h);
}

DEV void gld16(const u16* g, u16* l) {
  __builtin_amdgcn_global_load_lds((const __attribute__((address_space(1))) void*)g,
                                   (__attribute__((address_space(3))) void*)l, 16, 0, 0);
}

// ---------------------------------------------------------------- convert
__global__ void cvt_bf16(const float* __restrict__ s, u16* __restrict__ d, int n) {
  int i = blockIdx.x * 256 + threadIdx.x;
  if (i < n) d[i] = f2bf(s[i]);
}

// ---------------------------------------------------------------- layernorm (one wave per 512-row, bf16 out)
__global__ __launch_bounds__(256)
void ln_bf16(const float* __restrict__ src, const float* __restrict__ g,
             const float* __restrict__ b, u16* __restrict__ dst) {
  const int row = blockIdx.x * 4 + (threadIdx.x >> 6);
  const int lane = threadIdx.x & 63;
  const float* p = src + (long)row * 512 + lane * 8;
  float x[8];
  *(float4*)&x[0] = *(const float4*)p;
  *(float4*)&x[4] = *(const float4*)(p + 4);
  float s = 0.f;
#pragma unroll
  for (int e = 0; e < 8; ++e) s += x[e];
#pragma unroll
  for (int off = 32; off; off >>= 1) s += __shfl_xor(s, off, 64);
  const float mean = s * (1.0f / 512.0f);
  float q = 0.f;
#pragma unroll
  for (int e = 0; e < 8; ++e) { float d = x[e] - mean; q += d * d; }
#pragma unroll
  for (int off = 32; off; off >>= 1) q += __shfl_xor(q, off, 64);
  const float rinv = rsqrtf(q * (1.0f / 512.0f) + 1e-5f);
  u16 o[8];
  const int c0 = lane * 8;
#pragma unroll
  for (int e = 0; e < 8; ++e) o[e] = f2bf((x[e] - mean) * rinv * g[c0 + e] + b[c0 + e]);
  *(uint4*)(dst + (long)row * 512 + c0) = *(uint4*)o;
}

// ---------------------------------------------------------------- GEMM (NT), 128x256 tile.
// Round-4 lesson: 256x256 @ launch_bounds(512,4) forces acc spill (VGPR 64,
// 5 GB scratch writes). 128x256 halves per-wave acc to [4][4] (64 VGPR,
// ~115 total) so 4 waves/SIMD = 2 blocks/CU is register-feasible.
// 2-slot LDS ring = 48 KiB -> 2 blocks/CU (96 KiB). Cross-block MFMA/VMEM
// overlap (m114) is the latency-hiding mechanism; plain __syncthreads/K-tile.
// T2 piece-XOR swizzle retained (bank conflicts measured 0).
enum { EPI_QKV = 0, EPI_PROJ = 1, EPI_GELU = 2, EPI_FC2 = 3 };

constexpr int SLOT = 12288;  // elems per slot: A 128x32 (4096) + B 256x32 (8192)

template <int EPI>
__global__ __launch_bounds__(512, 4)
void gemm256(const u16* __restrict__ A, const u16* __restrict__ W,
             const float* __restrict__ bias, const float* __restrict__ res,
             void* __restrict__ outv, int M, int N, int K) {
  // LDS: 2 slots x 12288 elems = 49152 B
  extern __shared__ u16 sm[];
  (void)M;
  const int t = threadIdx.x;
  const int lane = t & 63;
  const int wave = t >> 6;
  const int wm = wave >> 2;   // 0..1 -> 64-row half of 128
  const int wn = wave & 3;    // 0..3 -> 64-col quarter of 256
  const long m0 = (long)blockIdx.y * 128;
  const long n0 = (long)blockIdx.x * 256;

  // staging: one gld16 instr = 512 thr x 16B = 128 rows x 64B. row = t>>2; physical piece t&3
  // holds global piece (t&3)^((row>>1)&3)  (T2 involution, source-side)
  const int sr = t >> 2;
  const int sc = ((t & 3) ^ ((sr >> 1) & 3)) * 8;
  const u16* gA0 = A + (m0 + sr) * (long)K + sc;           // A: 128 rows, 1 gld
  const u16* gB0 = W + (n0 + sr) * (long)K + sc;           // B: 256 rows, 2 glds
  const u16* gB1 = gB0 + 128L * K;
  u16* lws = sm + wave * 512;  // wave-uniform LDS base; HW adds lane*16B

  const int NT = K >> 5;  // K-tiles of 32
  f32x4 acc[4][4] = {};
  // read side: lane holds logical k-piece p=(lane>>4); physical piece = p ^ ((fr>>1)&3)
  // ((row>>1)&3) == ((fr>>1)&3): all sub-tile row bases are multiples of 16
  const int fr = lane & 15;
  const int kp = ((lane >> 4) ^ ((fr >> 1) & 3)) * 8;

#define STAGE(slot, tile)                      \
  do {                                         \
    const int _k = (tile) * 32;                \
    u16* _b = lws + (slot) * SLOT;             \
    gld16(gA0 + _k, _b);                       \
    gld16(gB0 + _k, _b + 4096);                \
    gld16(gB1 + _k, _b + 8192);                \
  } while (0)

#define COMPUTE(slot)                                                                           \
  do {                                                                                          \
    const u16* Ab = sm + (slot) * SLOT + (wm * 64 + fr) * 32 + kp;                              \
    const u16* Bb = sm + (slot) * SLOT + 4096 + (wn * 64 + fr) * 32 + kp;                       \
    bf16x8 af[4], bfv[4];                                                                       \
    _Pragma("unroll")                                                                           \
    for (int i = 0; i < 4; ++i) af[i] = *(const bf16x8*)(Ab + i * 512);                         \
    _Pragma("unroll")                                                                           \
    for (int j = 0; j < 4; ++j) bfv[j] = *(const bf16x8*)(Bb + j * 512);                        \
    __builtin_amdgcn_s_setprio(1);                                                              \
    _Pragma("unroll")                                                                           \
    for (int i = 0; i < 4; ++i)                                                                 \
      _Pragma("unroll")                                                                         \
      for (int j = 0; j < 4; ++j)                                                               \
        acc[i][j] = __builtin_amdgcn_mfma_f32_16x16x32_bf16(af[i], bfv[j], acc[i][j], 0, 0, 0); \
    __builtin_amdgcn_s_setprio(0);                                                              \
  } while (0)

  // prologue: stage tile 0 (drain at syncthreads)
  STAGE(0, 0);
  __syncthreads();

  // steady state: stage next slot, compute current, full sync (drain hidden by
  // the co-resident block on this CU)
  int kt = 0;
  for (; kt < NT - 1; ++kt) {
    STAGE((kt + 1) & 1, kt + 1);   // issue-early, before ds_reads of current
    COMPUTE(kt & 1);
    __syncthreads();
  }
  COMPUTE(kt & 1);
#undef STAGE
#undef COMPUTE

  // epilogue. C/D: col = lane&15, row = (lane>>4)*4 + reg
  const int col = lane & 15;
  const int rq = (lane >> 4) * 4;
#pragma unroll
  for (int mi = 0; mi < 4; ++mi) {
#pragma unroll
    for (int ni = 0; ni < 4; ++ni) {
#pragma unroll
      for (int r = 0; r < 4; ++r) {
        const long m = m0 + wm * 64 + mi * 16 + rq + r;
        const long n = n0 + wn * 64 + ni * 16 + col;
        const float v = acc[mi][ni][r] + bias[n];
        const long idx = m * (long)N + n;
        if constexpr (EPI == EPI_QKV) {
          ((u16*)outv)[idx] = f2bf(v);
        } else if constexpr (EPI == EPI_PROJ) {
          ((float*)outv)[idx] = v + res[idx];
        } else if constexpr (EPI == EPI_GELU) {
          ((u16*)outv)[idx] = f2bf(0.5f * v * (1.0f + erff(v * 0.70710678118f)));
        } else {  // EPI_FC2
          ((float*)outv)[idx] = v + res[idx];
        }
      }
    }
  }
}

// ---------------------------------------------------------------- MFMA windowed attention
// one block per window; 4 waves x 4 heads each
constexpr int SS_S = 68;  // S^T stride (elems); 8B-aligned b64 writes
constexpr int VT_S = 72;  // V^T stride (elems); 16B-aligned b128 reads

__global__ __launch_bounds__(256)
void attn_mfma(const u16* __restrict__ qkv, const float* __restrict__ mmap,
               const float* __restrict__ rpb, u16* __restrict__ outp) {
  __shared__ u16 SSb[4 * 64 * SS_S];   // 34816 B
  __shared__ u16 Vtb[4 * 32 * VT_S];   // 18432 B
  __shared__ u16 rpb_s[16 * 226];      // 7232 B
  __shared__ float mw[64];
  __shared__ int tok[64];
  __shared__ int regi[64];

  const int t = threadIdx.x;
  const int lane = t & 63, wave = t >> 6;
  const int c = lane & 15, q = lane >> 4;
  const int win = blockIdx.x;
  const int b = win >> 6, wh = (win >> 3) & 7, ww = win & 7;

  if (t < 64) {
    const int i = t >> 3, j = t & 7;
    const int hs = wh * 8 + i, wsv = ww * 8 + j;       // shifted-frame coords
    const int h = (hs + 4) & 63, w = (wsv + 4) & 63;   // original coords
    const int tk = b * 4096 + h * 64 + w;
    tok[t] = tk;
    mw[t] = fminf(fmaxf(mmap[tk], 0.f), 1.f);
    regi[t] = (hs < 56 ? 0 : (hs < 60 ? 1 : 2)) * 3 + (wsv < 56 ? 0 : (wsv < 60 ? 1 : 2));
  }
  for (int id = t; id < 3600; id += 256) {
    const int h = id & 15, idx = id >> 4;
    rpb_s[h * 226 + idx] = f2bf(rpb[id]);
  }
  __syncthreads();

  u16* SS = SSb + wave * 64 * SS_S;
  u16* Vt = Vtb + wave * 32 * VT_S;

  // hoisted per-lane state
  int tQ[4];
  float mwn[16], mwm[4];
  int rgn[16], rgm[4];
#pragma unroll
  for (int i = 0; i < 4; ++i) tQ[i] = tok[16 * i + c];
#pragma unroll
  for (int i = 0; i < 4; ++i)
#pragma unroll
    for (int r = 0; r < 4; ++r) {
      const int n = 16 * i + 4 * q + r;
      mwn[i * 4 + r] = mw[n];
      rgn[i * 4 + r] = regi[n];
    }
#pragma unroll
  for (int j = 0; j < 4; ++j) {
    const int m = 16 * j + c;
    mwm[j] = mw[m];
    rgm[j] = regi[m];
  }
  const int imc = c >> 3, jmc = c & 7;  // col m = 16j+c: im = 2j+imc, jm = jmc
  const int tV = tok[lane];
  const float scale = 0.17677669529663687f;  // 1/sqrt(32)

  for (int hi = 0; hi < 4; ++hi) {
    const int head = wave * 4 + hi;

    // Q/K fragments: A/B layout [m=lane&15][k=q*8+j], direct from global
    bf16x8 qf[4], kf[4];
#pragma unroll
    for (int i = 0; i < 4; ++i) {
      const u16* base = qkv + (long)tQ[i] * 1536 + head * 32 + q * 8;
      qf[i] = *(const bf16x8*)(base);
      kf[i] = *(const bf16x8*)(base + 512);
    }

    // stage V transposed: Vt[d][token]
    {
      const u16* vp = qkv + (long)tV * 1536 + 1024 + head * 32;
      u16 vv[32];
      *(uint4*)&vv[0]  = *(const uint4*)(vp);
      *(uint4*)&vv[8]  = *(const uint4*)(vp + 8);
      *(uint4*)&vv[16] = *(const uint4*)(vp + 16);
      *(uint4*)&vv[24] = *(const uint4*)(vp + 24);
#pragma unroll
      for (int d = 0; d < 32; ++d) Vt[d * VT_S + lane] = vv[d];
    }

    // QK^T: S[n][m], tiles i (rows n), j (cols m)
    f32x4 acc[4][4] = {};
#pragma unroll
    for (int i = 0; i < 4; ++i)
#pragma unroll
      for (int j = 0; j < 4; ++j)
        acc[i][j] = __builtin_amdgcn_mfma_f32_16x16x32_bf16(qf[i], kf[j], acc[i][j], 0, 0, 0);

    // bias + softmax in registers (lane holds rows n=16i+4q+r, cols m=16j+c)
    const u16* rb = rpb_s + head * 226;
    float rmx[16], rsum[16];
#pragma unroll
    for (int i = 0; i < 4; ++i)
#pragma unroll
      for (int r = 0; r < 4; ++r) {
        const int n = 16 * i + 4 * q + r;
        const int inr = n >> 3, jnr = n & 7;
        float mx = -1e30f;
#pragma unroll
        for (int j = 0; j < 4; ++j) {
          const int di = inr - 2 * j - imc + 7;
          const int dj = jnr - jmc + 7;
          float s = acc[i][j][r] * scale + bf2f(rb[di * 15 + dj]) +
                    0.5f * (mwn[i * 4 + r] + mwm[j]);
          if (rgn[i * 4 + r] != rgm[j]) s -= 100.f;
          acc[i][j][r] = s;
          mx = fmaxf(mx, s);
        }
        rmx[i * 4 + r] = mx;
      }
#pragma unroll
    for (int ir = 0; ir < 16; ++ir)
#pragma unroll
      for (int msk = 1; msk < 16; msk <<= 1)
        rmx[ir] = fmaxf(rmx[ir], __shfl_xor(rmx[ir], msk, 64));
#pragma unroll
    for (int i = 0; i < 4; ++i)
#pragma unroll
      for (int r = 0; r < 4; ++r) {
        float sm = 0.f;
#pragma unroll
        for (int j = 0; j < 4; ++j) {
          const float e = __expf(acc[i][j][r] - rmx[i * 4 + r]);
          acc[i][j][r] = e;
          sm += e;
        }
        rsum[i * 4 + r] = sm;
      }
#pragma unroll
    for (int ir = 0; ir < 16; ++ir) {
#pragma unroll
      for (int msk = 1; msk < 16; msk <<= 1)
        rsum[ir] += __shfl_xor(rsum[ir], msk, 64);
      rsum[ir] = 1.0f / rsum[ir];
    }

    // write SS = S^T (bf16), packed b64: SS[m][n..n+3]
#pragma unroll
    for (int i = 0; i < 4; ++i)
#pragma unroll
      for (int j = 0; j < 4; ++j) {
        ushort4 pk;
        pk.x = f2bf(acc[i][j][0] * rsum[i * 4 + 0]);
        pk.y = f2bf(acc[i][j][1] * rsum[i * 4 + 1]);
        pk.z = f2bf(acc[i][j][2] * rsum[i * 4 + 2]);
        pk.w = f2bf(acc[i][j][3] * rsum[i * 4 + 3]);
        *(ushort4*)&SS[(16 * j + c) * SS_S + 16 * i + 4 * q] = pk;
      }

    __syncthreads();  // writes (Vt, SS) -> reads, all waves in lockstep

    // PV: O^T = Vt(32x64) * S^T(64x64)
    bf16x8 av[2][2];
#pragma unroll
    for (int mi = 0; mi < 2; ++mi)
#pragma unroll
      for (int ki = 0; ki < 2; ++ki)
        av[mi][ki] = *(const bf16x8*)&Vt[(16 * mi + c) * VT_S + 32 * ki + 8 * q];

    f32x4 oacc[2][4] = {};
#pragma unroll
    for (int ki = 0; ki < 2; ++ki)
#pragma unroll
      for (int ni = 0; ni < 4; ++ni) {
        union { u16 h[8]; bf16x8 v; } ub;
#pragma unroll
        for (int jj = 0; jj < 8; ++jj)
          ub.h[jj] = SS[(32 * ki + 8 * q + jj) * SS_S + 16 * ni + c];
#pragma unroll
        for (int mi = 0; mi < 2; ++mi)
          oacc[mi][ni] = __builtin_amdgcn_mfma_f32_16x16x32_bf16(av[mi][ki], ub.v, oacc[mi][ni], 0, 0, 0);
      }

    // store O: D col = token n = 16ni+c, row = d = 16mi+4q+r (r contiguous -> 8B stores)
#pragma unroll
    for (int ni = 0; ni < 4; ++ni) {
      u16* ob = outp + (long)tQ[ni] * 512 + head * 32;
#pragma unroll
      for (int mi = 0; mi < 2; ++mi) {
        ushort4 pk;
        pk.x = f2bf(oacc[mi][ni][0]);
        pk.y = f2bf(oacc[mi][ni][1]);
        pk.z = f2bf(oacc[mi][ni][2]);
        pk.w = f2bf(oacc[mi][ni][3]);
        *(ushort4*)(ob + 16 * mi + 4 * q) = pk;
      }
    }
    __syncthreads();  // reads done before next iteration's writes
  }
}

// ---------------------------------------------------------------- launch
extern "C" void kernel_launch(void* const* d_in, const int* in_sizes, int n_in,
                              void* d_out, int out_size, void* d_ws, size_t ws_size,
                              hipStream_t stream) {
  (void)in_sizes; (void)n_in; (void)out_size; (void)ws_size;
  const float* x      = (const float*)d_in[0];
  const float* mmap   = (const float*)d_in[1];
  const float* n1g    = (const float*)d_in[2];
  const float* n1b    = (const float*)d_in[3];
  const float* qkv_w  = (const float*)d_in[4];
  const float* qkv_b  = (const float*)d_in[5];
  const float* proj_w = (const float*)d_in[6];
  const float* proj_b = (const float*)d_in[7];
  const float* rpb    = (const float*)d_in[8];
  const float* n2g    = (const float*)d_in[9];
  const float* n2b    = (const float*)d_in[10];
  const float* fc1_w  = (const float*)d_in[11];
  const float* fc1_b  = (const float*)d_in[12];
  const float* fc2_w  = (const float*)d_in[13];
  const float* fc2_b  = (const float*)d_in[14];
  float* out = (float*)d_out;
  char* ws = (char*)d_ws;

  u16*   ybf   = (u16*)(ws);                  // 64 MB : LN1 out, later LN2 out
  u16*   qkvbf = (u16*)(ws + (64L  << 20));   // 192 MB
  u16*   attno = (u16*)(ws + (256L << 20));   // 64 MB
  float* x1    = (float*)(ws + (320L << 20)); // 128 MB
  u16*   hbuf  = qkvbf;                       // 256 MB, reuses qkvbf+attno region
  u16*   wqkv  = (u16*)(ws + (448L << 20));
  u16*   wproj = wqkv + 1536 * 512;
  u16*   wfc1  = wproj + 512 * 512;
  u16*   wfc2  = wfc1 + 2048 * 512;

  static bool smem_init = false;
  if (!smem_init) {
    smem_init = true;
    (void)hipFuncSetAttribute(reinterpret_cast<const void*>(gemm256<EPI_QKV>),
                              hipFuncAttributeMaxDynamicSharedMemorySize, 49152);
    (void)hipFuncSetAttribute(reinterpret_cast<const void*>(gemm256<EPI_PROJ>),
                              hipFuncAttributeMaxDynamicSharedMemorySize, 49152);
    (void)hipFuncSetAttribute(reinterpret_cast<const void*>(gemm256<EPI_GELU>),
                              hipFuncAttributeMaxDynamicSharedMemorySize, 49152);
    (void)hipFuncSetAttribute(reinterpret_cast<const void*>(gemm256<EPI_FC2>),
                              hipFuncAttributeMaxDynamicSharedMemorySize, 49152);
  }

  cvt_bf16<<<1536 * 512 / 256, 256, 0, stream>>>(qkv_w, wqkv, 1536 * 512);
  cvt_bf16<<<512 * 512 / 256, 256, 0, stream>>>(proj_w, wproj, 512 * 512);
  cvt_bf16<<<2048 * 512 / 256, 256, 0, stream>>>(fc1_w, wfc1, 2048 * 512);
  cvt_bf16<<<512 * 2048 / 256, 256, 0, stream>>>(fc2_w, wfc2, 512 * 2048);

  ln_bf16<<<16384, 256, 0, stream>>>(x, n1g, n1b, ybf);
  gemm256<EPI_QKV><<<dim3(6, 512), 512, 49152, stream>>>(ybf, wqkv, qkv_b, nullptr, qkvbf, 65536, 1536, 512);
  attn_mfma<<<1024, 256, 0, stream>>>(qkvbf, mmap, rpb, attno);
  gemm256<EPI_PROJ><<<dim3(2, 512), 512, 49152, stream>>>(attno, wproj, proj_b, x, x1, 65536, 512, 512);
  ln_bf16<<<16384, 256, 0, stream>>>(x1, n2g, n2b, ybf);
  gemm256<EPI_GELU><<<dim3(8, 512), 512, 49152, stream>>>(ybf, wfc1, fc1_b, nullptr, hbuf, 65536, 2048, 512);
  gemm256<EPI_FC2><<<dim3(2, 512), 512, 49152, stream>>>(hbuf, wfc2, fc2_b, x1, out, 65536, 512, 2048);
}

// Round 6
// 1047.380 us; speedup vs baseline: 5.2375x; 1.0029x over previous
//
#include <hip/hip_runtime.h>
#include <hip/hip_bf16.h>

typedef unsigned short u16;
typedef unsigned int u32;
typedef __attribute__((ext_vector_type(4))) float f32x4;
typedef __attribute__((ext_vector_type(8))) short bf16x8;

#define DEV static __device__ __forceinline__

DEV float bf2f(u16 u) { u32 x = ((u32)u) << 16; return __builtin_bit_cast(float, x); }
DEV u16 f2bf(float f) {
  __hip_bfloat16 h = __float2bfloat16(f);
  return __builtin_bit_cast(u16, h);
}

// GELU exact-grade: erf via Abramowitz-Stegun 7.1.26 (|err| < 1.5e-7,
// far below bf16 output rounding). ~15 VALU vs ~30+ for ocml erff.
DEV float fast_gelu(float x) {
  const float ax = fabsf(x) * 0.70710678118f;  // |x|/sqrt(2)
  const float t = __builtin_amdgcn_rcpf(1.0f + 0.3275911f * ax);
  const float poly =
      t * (0.254829592f +
           t * (-0.284496736f + t * (1.421413741f + t * (-1.453152027f + t * 1.061405429f))));
  const float e = __expf(-ax * ax);
  float er = 1.0f - poly * e;
  er = __builtin_copysignf(er, x);
  return 0.5f * x * (1.0f + er);
}

DEV void gld16(const u16* g, u16* l) {
  __builtin_amdgcn_global_load_lds((const __attribute__((address_space(1))) void*)g,
                                   (__attribute__((address_space(3))) void*)l, 16, 0, 0);
}

// ---------------------------------------------------------------- convert
__global__ void cvt_bf16(const float* __restrict__ s, u16* __restrict__ d, int n) {
  int i = blockIdx.x * 256 + threadIdx.x;
  if (i < n) d[i] = f2bf(s[i]);
}

// ---------------------------------------------------------------- layernorm (one wave per 512-row, bf16 out)
__global__ __launch_bounds__(256)
void ln_bf16(const float* __restrict__ src, const float* __restrict__ g,
             const float* __restrict__ b, u16* __restrict__ dst) {
  const int row = blockIdx.x * 4 + (threadIdx.x >> 6);
  const int lane = threadIdx.x & 63;
  const float* p = src + (long)row * 512 + lane * 8;
  float x[8];
  *(float4*)&x[0] = *(const float4*)p;
  *(float4*)&x[4] = *(const float4*)(p + 4);
  float s = 0.f;
#pragma unroll
  for (int e = 0; e < 8; ++e) s += x[e];
#pragma unroll
  for (int off = 32; off; off >>= 1) s += __shfl_xor(s, off, 64);
  const float mean = s * (1.0f / 512.0f);
  float q = 0.f;
#pragma unroll
  for (int e = 0; e < 8; ++e) { float d = x[e] - mean; q += d * d; }
#pragma unroll
  for (int off = 32; off; off >>= 1) q += __shfl_xor(q, off, 64);
  const float rinv = rsqrtf(q * (1.0f / 512.0f) + 1e-5f);
  u16 o[8];
  const int c0 = lane * 8;
#pragma unroll
  for (int e = 0; e < 8; ++e) o[e] = f2bf((x[e] - mean) * rinv * g[c0 + e] + b[c0 + e]);
  *(uint4*)(dst + (long)row * 512 + c0) = *(uint4*)o;
}

// ---------------------------------------------------------------- GEMM (NT), 128x256 tile.
// 2 blocks/CU (verified r5: occupancy 40%, MfmaUtil 23->27, 224 us FC1).
// This round: (a) 3-slot LDS ring (72 KiB/block, still 2 blocks/CU) with
// counted vmcnt(3) + raw s_barrier -> waited tile was issued 2 iterations
// earlier, no per-K-tile HBM-latency exposure; (b) epilogue VALU diet:
// fast_gelu (A&S erf), hoisted bias, row-pointer + immediate-offset stores.
// T2 piece-XOR swizzle retained (bank conflicts measured 0).
enum { EPI_QKV = 0, EPI_PROJ = 1, EPI_GELU = 2, EPI_FC2 = 3 };

constexpr int SLOT = 12288;  // elems per slot: A 128x32 (4096) + B 256x32 (8192)

template <int EPI>
__global__ __launch_bounds__(512, 4)
void gemm256(const u16* __restrict__ A, const u16* __restrict__ W,
             const float* __restrict__ bias, const float* __restrict__ res,
             void* __restrict__ outv, int M, int N, int K) {
  // LDS: 3 slots x 12288 elems = 73728 B
  extern __shared__ u16 sm[];
  (void)M;
  const int t = threadIdx.x;
  const int lane = t & 63;
  const int wave = t >> 6;
  const int wm = wave >> 2;   // 0..1 -> 64-row half of 128
  const int wn = wave & 3;    // 0..3 -> 64-col quarter of 256
  const long m0 = (long)blockIdx.y * 128;
  const long n0 = (long)blockIdx.x * 256;

  // staging: one gld16 instr = 512 thr x 16B = 128 rows x 64B. row = t>>2; physical piece t&3
  // holds global piece (t&3)^((row>>1)&3)  (T2 involution, source-side)
  const int sr = t >> 2;
  const int sc = ((t & 3) ^ ((sr >> 1) & 3)) * 8;
  const u16* gA0 = A + (m0 + sr) * (long)K + sc;           // A: 128 rows, 1 gld
  const u16* gB0 = W + (n0 + sr) * (long)K + sc;           // B: 256 rows, 2 glds
  const u16* gB1 = gB0 + 128L * K;
  u16* lws = sm + wave * 512;  // wave-uniform LDS base; HW adds lane*16B

  const int NT = K >> 5;  // K-tiles of 32
  f32x4 acc[4][4] = {};
  // read side: lane holds logical k-piece p=(lane>>4); physical piece = p ^ ((fr>>1)&3)
  const int fr = lane & 15;
  const int kp = ((lane >> 4) ^ ((fr >> 1) & 3)) * 8;

#define STAGE(slot, tile)                      \
  do {                                         \
    const int _k = (tile) * 32;                \
    u16* _b = lws + (slot) * SLOT;             \
    gld16(gA0 + _k, _b);                       \
    gld16(gB0 + _k, _b + 4096);                \
    gld16(gB1 + _k, _b + 8192);                \
  } while (0)

#define COMPUTE(slot)                                                                           \
  do {                                                                                          \
    const u16* Ab = sm + (slot) * SLOT + (wm * 64 + fr) * 32 + kp;                              \
    const u16* Bb = sm + (slot) * SLOT + 4096 + (wn * 64 + fr) * 32 + kp;                       \
    bf16x8 af[4], bfv[4];                                                                       \
    _Pragma("unroll")                                                                           \
    for (int i = 0; i < 4; ++i) af[i] = *(const bf16x8*)(Ab + i * 512);                         \
    _Pragma("unroll")                                                                           \
    for (int j = 0; j < 4; ++j) bfv[j] = *(const bf16x8*)(Bb + j * 512);                        \
    __builtin_amdgcn_s_setprio(1);                                                              \
    _Pragma("unroll")                                                                           \
    for (int i = 0; i < 4; ++i)                                                                 \
      _Pragma("unroll")                                                                         \
      for (int j = 0; j < 4; ++j)                                                               \
        acc[i][j] = __builtin_amdgcn_mfma_f32_16x16x32_bf16(af[i], bfv[j], acc[i][j], 0, 0, 0); \
    __builtin_amdgcn_s_setprio(0);                                                              \
  } while (0)

  // prologue: prime 2 tiles; wait tile0 (leave tile1's 3 loads in flight)
  STAGE(0, 0);
  STAGE(1, 1);
  asm volatile("s_waitcnt vmcnt(3)" ::: "memory");
  __builtin_amdgcn_s_barrier();
  asm volatile("" ::: "memory");

  // steady state: entry invariant = tile kt landed & visible; slot being
  // staged (kt+2)%3 was last read at iter kt-1, barrier-ordered.
  int cs = 0, ss = 2;
  int kt = 0;
  for (; kt < NT - 2; ++kt) {
    STAGE(ss, kt + 2);
    COMPUTE(cs);
    asm volatile("s_waitcnt vmcnt(3)" ::: "memory");  // tile kt+1 landed; kt+2 in flight
    __builtin_amdgcn_s_barrier();
    asm volatile("" ::: "memory");
    cs = cs == 2 ? 0 : cs + 1;
    ss = ss == 2 ? 0 : ss + 1;
  }
  // tails: kt = NT-2, NT-1
  COMPUTE(cs);
  asm volatile("s_waitcnt vmcnt(0)" ::: "memory");
  __builtin_amdgcn_s_barrier();
  asm volatile("" ::: "memory");
  cs = cs == 2 ? 0 : cs + 1;
  COMPUTE(cs);
#undef STAGE
#undef COMPUTE

  // epilogue. C/D: col = lane&15, row = (lane>>4)*4 + reg.
  // bias hoisted (4 loads); per-(mi,r) row base; ni*16 folds into store offset.
  const int col = lane & 15;
  const int rq = (lane >> 4) * 4;
  const long ncol = n0 + wn * 64 + col;
  float bv[4];
#pragma unroll
  for (int ni = 0; ni < 4; ++ni) bv[ni] = bias[ncol + ni * 16];
#pragma unroll
  for (int mi = 0; mi < 4; ++mi) {
#pragma unroll
    for (int r = 0; r < 4; ++r) {
      const long m = m0 + wm * 64 + mi * 16 + rq + r;
      const long base = m * (long)N + ncol;
      if constexpr (EPI == EPI_QKV) {
        u16* p = (u16*)outv + base;
#pragma unroll
        for (int ni = 0; ni < 4; ++ni) p[ni * 16] = f2bf(acc[mi][ni][r] + bv[ni]);
      } else if constexpr (EPI == EPI_PROJ) {
        float* p = (float*)outv + base;
        const float* rp = res + base;
#pragma unroll
        for (int ni = 0; ni < 4; ++ni) p[ni * 16] = acc[mi][ni][r] + bv[ni] + rp[ni * 16];
      } else if constexpr (EPI == EPI_GELU) {
        u16* p = (u16*)outv + base;
#pragma unroll
        for (int ni = 0; ni < 4; ++ni) p[ni * 16] = f2bf(fast_gelu(acc[mi][ni][r] + bv[ni]));
      } else {  // EPI_FC2
        float* p = (float*)outv + base;
        const float* rp = res + base;
#pragma unroll
        for (int ni = 0; ni < 4; ++ni) p[ni * 16] = acc[mi][ni][r] + bv[ni] + rp[ni * 16];
      }
    }
  }
}

// ---------------------------------------------------------------- MFMA windowed attention
// one block per window; 4 waves x 4 heads each
constexpr int SS_S = 68;  // S^T stride (elems); 8B-aligned b64 writes
constexpr int VT_S = 72;  // V^T stride (elems); 16B-aligned b128 reads

__global__ __launch_bounds__(256)
void attn_mfma(const u16* __restrict__ qkv, const float* __restrict__ mmap,
               const float* __restrict__ rpb, u16* __restrict__ outp) {
  __shared__ u16 SSb[4 * 64 * SS_S];   // 34816 B
  __shared__ u16 Vtb[4 * 32 * VT_S];   // 18432 B
  __shared__ u16 rpb_s[16 * 226];      // 7232 B
  __shared__ float mw[64];
  __shared__ int tok[64];
  __shared__ int regi[64];

  const int t = threadIdx.x;
  const int lane = t & 63, wave = t >> 6;
  const int c = lane & 15, q = lane >> 4;
  const int win = blockIdx.x;
  const int b = win >> 6, wh = (win >> 3) & 7, ww = win & 7;

  if (t < 64) {
    const int i = t >> 3, j = t & 7;
    const int hs = wh * 8 + i, wsv = ww * 8 + j;       // shifted-frame coords
    const int h = (hs + 4) & 63, w = (wsv + 4) & 63;   // original coords
    const int tk = b * 4096 + h * 64 + w;
    tok[t] = tk;
    mw[t] = fminf(fmaxf(mmap[tk], 0.f), 1.f);
    regi[t] = (hs < 56 ? 0 : (hs < 60 ? 1 : 2)) * 3 + (wsv < 56 ? 0 : (wsv < 60 ? 1 : 2));
  }
  for (int id = t; id < 3600; id += 256) {
    const int h = id & 15, idx = id >> 4;
    rpb_s[h * 226 + idx] = f2bf(rpb[id]);
  }
  __syncthreads();

  u16* SS = SSb + wave * 64 * SS_S;
  u16* Vt = Vtb + wave * 32 * VT_S;

  // hoisted per-lane state
  int tQ[4];
  float mwn[16], mwm[4];
  int rgn[16], rgm[4];
#pragma unroll
  for (int i = 0; i < 4; ++i) tQ[i] = tok[16 * i + c];
#pragma unroll
  for (int i = 0; i < 4; ++i)
#pragma unroll
    for (int r = 0; r < 4; ++r) {
      const int n = 16 * i + 4 * q + r;
      mwn[i * 4 + r] = mw[n];
      rgn[i * 4 + r] = regi[n];
    }
#pragma unroll
  for (int j = 0; j < 4; ++j) {
    const int m = 16 * j + c;
    mwm[j] = mw[m];
    rgm[j] = regi[m];
  }
  const int imc = c >> 3, jmc = c & 7;  // col m = 16j+c: im = 2j+imc, jm = jmc
  const int tV = tok[lane];
  const float scale = 0.17677669529663687f;  // 1/sqrt(32)

  for (int hi = 0; hi < 4; ++hi) {
    const int head = wave * 4 + hi;

    // Q/K fragments: A/B layout [m=lane&15][k=q*8+j], direct from global
    bf16x8 qf[4], kf[4];
#pragma unroll
    for (int i = 0; i < 4; ++i) {
      const u16* base = qkv + (long)tQ[i] * 1536 + head * 32 + q * 8;
      qf[i] = *(const bf16x8*)(base);
      kf[i] = *(const bf16x8*)(base + 512);
    }

    // stage V transposed: Vt[d][token]
    {
      const u16* vp = qkv + (long)tV * 1536 + 1024 + head * 32;
      u16 vv[32];
      *(uint4*)&vv[0]  = *(const uint4*)(vp);
      *(uint4*)&vv[8]  = *(const uint4*)(vp + 8);
      *(uint4*)&vv[16] = *(const uint4*)(vp + 16);
      *(uint4*)&vv[24] = *(const uint4*)(vp + 24);
#pragma unroll
      for (int d = 0; d < 32; ++d) Vt[d * VT_S + lane] = vv[d];
    }

    // QK^T: S[n][m], tiles i (rows n), j (cols m)
    f32x4 acc[4][4] = {};
#pragma unroll
    for (int i = 0; i < 4; ++i)
#pragma unroll
      for (int j = 0; j < 4; ++j)
        acc[i][j] = __builtin_amdgcn_mfma_f32_16x16x32_bf16(qf[i], kf[j], acc[i][j], 0, 0, 0);

    // bias + softmax in registers (lane holds rows n=16i+4q+r, cols m=16j+c)
    const u16* rb = rpb_s + head * 226;
    float rmx[16], rsum[16];
#pragma unroll
    for (int i = 0; i < 4; ++i)
#pragma unroll
      for (int r = 0; r < 4; ++r) {
        const int n = 16 * i + 4 * q + r;
        const int inr = n >> 3, jnr = n & 7;
        float mx = -1e30f;
#pragma unroll
        for (int j = 0; j < 4; ++j) {
          const int di = inr - 2 * j - imc + 7;
          const int dj = jnr - jmc + 7;
          float s = acc[i][j][r] * scale + bf2f(rb[di * 15 + dj]) +
                    0.5f * (mwn[i * 4 + r] + mwm[j]);
          if (rgn[i * 4 + r] != rgm[j]) s -= 100.f;
          acc[i][j][r] = s;
          mx = fmaxf(mx, s);
        }
        rmx[i * 4 + r] = mx;
      }
#pragma unroll
    for (int ir = 0; ir < 16; ++ir)
#pragma unroll
      for (int msk = 1; msk < 16; msk <<= 1)
        rmx[ir] = fmaxf(rmx[ir], __shfl_xor(rmx[ir], msk, 64));
#pragma unroll
    for (int i = 0; i < 4; ++i)
#pragma unroll
      for (int r = 0; r < 4; ++r) {
        float sm = 0.f;
#pragma unroll
        for (int j = 0; j < 4; ++j) {
          const float e = __expf(acc[i][j][r] - rmx[i * 4 + r]);
          acc[i][j][r] = e;
          sm += e;
        }
        rsum[i * 4 + r] = sm;
      }
#pragma unroll
    for (int ir = 0; ir < 16; ++ir) {
#pragma unroll
      for (int msk = 1; msk < 16; msk <<= 1)
        rsum[ir] += __shfl_xor(rsum[ir], msk, 64);
      rsum[ir] = 1.0f / rsum[ir];
    }

    // write SS = S^T (bf16), packed b64: SS[m][n..n+3]
#pragma unroll
    for (int i = 0; i < 4; ++i)
#pragma unroll
      for (int j = 0; j < 4; ++j) {
        ushort4 pk;
        pk.x = f2bf(acc[i][j][0] * rsum[i * 4 + 0]);
        pk.y = f2bf(acc[i][j][1] * rsum[i * 4 + 1]);
        pk.z = f2bf(acc[i][j][2] * rsum[i * 4 + 2]);
        pk.w = f2bf(acc[i][j][3] * rsum[i * 4 + 3]);
        *(ushort4*)&SS[(16 * j + c) * SS_S + 16 * i + 4 * q] = pk;
      }

    __syncthreads();  // writes (Vt, SS) -> reads, all waves in lockstep

    // PV: O^T = Vt(32x64) * S^T(64x64)
    bf16x8 av[2][2];
#pragma unroll
    for (int mi = 0; mi < 2; ++mi)
#pragma unroll
      for (int ki = 0; ki < 2; ++ki)
        av[mi][ki] = *(const bf16x8*)&Vt[(16 * mi + c) * VT_S + 32 * ki + 8 * q];

    f32x4 oacc[2][4] = {};
#pragma unroll
    for (int ki = 0; ki < 2; ++ki)
#pragma unroll
      for (int ni = 0; ni < 4; ++ni) {
        union { u16 h[8]; bf16x8 v; } ub;
#pragma unroll
        for (int jj = 0; jj < 8; ++jj)
          ub.h[jj] = SS[(32 * ki + 8 * q + jj) * SS_S + 16 * ni + c];
#pragma unroll
        for (int mi = 0; mi < 2; ++mi)
          oacc[mi][ni] = __builtin_amdgcn_mfma_f32_16x16x32_bf16(av[mi][ki], ub.v, oacc[mi][ni], 0, 0, 0);
      }

    // store O: D col = token n = 16ni+c, row = d = 16mi+4q+r (r contiguous -> 8B stores)
#pragma unroll
    for (int ni = 0; ni < 4; ++ni) {
      u16* ob = outp + (long)tQ[ni] * 512 + head * 32;
#pragma unroll
      for (int mi = 0; mi < 2; ++mi) {
        ushort4 pk;
        pk.x = f2bf(oacc[mi][ni][0]);
        pk.y = f2bf(oacc[mi][ni][1]);
        pk.z = f2bf(oacc[mi][ni][2]);
        pk.w = f2bf(oacc[mi][ni][3]);
        *(ushort4*)(ob + 16 * mi + 4 * q) = pk;
      }
    }
    __syncthreads();  // reads done before next iteration's writes
  }
}

// ---------------------------------------------------------------- launch
extern "C" void kernel_launch(void* const* d_in, const int* in_sizes, int n_in,
                              void* d_out, int out_size, void* d_ws, size_t ws_size,
                              hipStream_t stream) {
  (void)in_sizes; (void)n_in; (void)out_size; (void)ws_size;
  const float* x      = (const float*)d_in[0];
  const float* mmap   = (const float*)d_in[1];
  const float* n1g    = (const float*)d_in[2];
  const float* n1b    = (const float*)d_in[3];
  const float* qkv_w  = (const float*)d_in[4];
  const float* qkv_b  = (const float*)d_in[5];
  const float* proj_w = (const float*)d_in[6];
  const float* proj_b = (const float*)d_in[7];
  const float* rpb    = (const float*)d_in[8];
  const float* n2g    = (const float*)d_in[9];
  const float* n2b    = (const float*)d_in[10];
  const float* fc1_w  = (const float*)d_in[11];
  const float* fc1_b  = (const float*)d_in[12];
  const float* fc2_w  = (const float*)d_in[13];
  const float* fc2_b  = (const float*)d_in[14];
  float* out = (float*)d_out;
  char* ws = (char*)d_ws;

  u16*   ybf   = (u16*)(ws);                  // 64 MB : LN1 out, later LN2 out
  u16*   qkvbf = (u16*)(ws + (64L  << 20));   // 192 MB
  u16*   attno = (u16*)(ws + (256L << 20));   // 64 MB
  float* x1    = (float*)(ws + (320L << 20)); // 128 MB
  u16*   hbuf  = qkvbf;                       // 256 MB, reuses qkvbf+attno region
  u16*   wqkv  = (u16*)(ws + (448L << 20));
  u16*   wproj = wqkv + 1536 * 512;
  u16*   wfc1  = wproj + 512 * 512;
  u16*   wfc2  = wfc1 + 2048 * 512;

  static bool smem_init = false;
  if (!smem_init) {
    smem_init = true;
    (void)hipFuncSetAttribute(reinterpret_cast<const void*>(gemm256<EPI_QKV>),
                              hipFuncAttributeMaxDynamicSharedMemorySize, 73728);
    (void)hipFuncSetAttribute(reinterpret_cast<const void*>(gemm256<EPI_PROJ>),
                              hipFuncAttributeMaxDynamicSharedMemorySize, 73728);
    (void)hipFuncSetAttribute(reinterpret_cast<const void*>(gemm256<EPI_GELU>),
                              hipFuncAttributeMaxDynamicSharedMemorySize, 73728);
    (void)hipFuncSetAttribute(reinterpret_cast<const void*>(gemm256<EPI_FC2>),
                              hipFuncAttributeMaxDynamicSharedMemorySize, 73728);
  }

  cvt_bf16<<<1536 * 512 / 256, 256, 0, stream>>>(qkv_w, wqkv, 1536 * 512);
  cvt_bf16<<<512 * 512 / 256, 256, 0, stream>>>(proj_w, wproj, 512 * 512);
  cvt_bf16<<<2048 * 512 / 256, 256, 0, stream>>>(fc1_w, wfc1, 2048 * 512);
  cvt_bf16<<<512 * 2048 / 256, 256, 0, stream>>>(fc2_w, wfc2, 512 * 2048);

  ln_bf16<<<16384, 256, 0, stream>>>(x, n1g, n1b, ybf);
  gemm256<EPI_QKV><<<dim3(6, 512), 512, 73728, stream>>>(ybf, wqkv, qkv_b, nullptr, qkvbf, 65536, 1536, 512);
  attn_mfma<<<1024, 256, 0, stream>>>(qkvbf, mmap, rpb, attno);
  gemm256<EPI_PROJ><<<dim3(2, 512), 512, 73728, stream>>>(attno, wproj, proj_b, x, x1, 65536, 512, 512);
  ln_bf16<<<16384, 256, 0, stream>>>(x1, n2g, n2b, ybf);
  gemm256<EPI_GELU><<<dim3(8, 512), 512, 73728, stream>>>(ybf, wfc1, fc1_b, nullptr, hbuf, 65536, 2048, 512);
  gemm256<EPI_FC2><<<dim3(2, 512), 512, 73728, stream>>>(hbuf, wfc2, fc2_b, x1, out, 65536, 512, 2048);
}